// Round 1
// baseline (181.246 us; speedup 1.0000x reference)
//
#include <hip/hip_runtime.h>

// Causal MHA forward, B=2 T=2048 C=1024 H=16 hs=64, fp32 in/out, bf16 MFMA internally.
// R11: flash kernel only — double-buffered K/V staging with raw s_barrier + explicit
// s_waitcnt vmcnt(0) (one barrier per KV tile; prefetch latency hidden under compute),
// + s_setprio around MFMA pairs. Everything else identical to R10 (measured 179.7us,
// flash 42.4us @ MfmaUtil 15% / VALUBusy 34% -> latency-bound).

typedef unsigned short u16;
typedef unsigned int u32;
typedef __bf16 bf16x8 __attribute__((ext_vector_type(8)));
typedef float f32x4 __attribute__((ext_vector_type(4)));
typedef u32 u32x4 __attribute__((ext_vector_type(4)));
typedef u16 u16x4 __attribute__((ext_vector_type(4)));

__device__ __forceinline__ u16 f2bf(float f) {
  u32 u = __float_as_uint(f);
  u32 r = u + 0x7FFFu + ((u >> 16) & 1u);  // RNE, finite inputs only
  return (u16)(r >> 16);
}

__device__ __forceinline__ bf16x8 ld_bf8(const u16* p) {
  union { u32x4 u; bf16x8 b; } x;
  x.u = *(const u32x4*)p;
  return x.b;
}

__device__ __forceinline__ void gld_lds16(const u16* g, u16* l) {
  __builtin_amdgcn_global_load_lds(
      (const __attribute__((address_space(1))) u32*)g,
      (__attribute__((address_space(3))) u32*)l, 16, 0, 0);
}

// ---- merged prep: fp32->bf16 x-convert + both weight transpose-converts ----
__device__ __forceinline__ void convT_body(const float* __restrict__ src,
                                           u16* __restrict__ dst, int R, int Cc,
                                           int r0, int c0, float* ls /*64x65*/) {
  int t = threadIdx.x;
  for (int u = t; u < 1024; u += 256) {
    int r = u >> 4, cs = (u & 15) << 2;
    float4 v = *(const float4*)&src[(size_t)(r0 + r) * Cc + (c0 + cs)];
    ls[r * 65 + cs] = v.x; ls[r * 65 + cs + 1] = v.y;
    ls[r * 65 + cs + 2] = v.z; ls[r * 65 + cs + 3] = v.w;
  }
  __syncthreads();
  for (int u = t; u < 1024; u += 256) {
    int n = u >> 4, ks = (u & 15) << 2;
    u16x4 o;
    o.x = f2bf(ls[ks * 65 + n]); o.y = f2bf(ls[(ks + 1) * 65 + n]);
    o.z = f2bf(ls[(ks + 2) * 65 + n]); o.w = f2bf(ls[(ks + 3) * 65 + n]);
    *(u16x4*)&dst[(size_t)(c0 + n) * R + (r0 + ks)] = o;
  }
}

__global__ __launch_bounds__(256) void prep_kernel(
    const float* __restrict__ x, const float* __restrict__ Wkqv,
    const float* __restrict__ Wproj, u16* __restrict__ xb,
    u16* __restrict__ wkqvT, u16* __restrict__ wprojT) {
  __shared__ float ls[64 * 65];
  int bx = blockIdx.x;
  if (bx < 2048) {  // x -> bf16, 8 elems/thread
    int idx = bx * 256 + threadIdx.x;
    const float4* s4 = (const float4*)x;
    float4 a = s4[2 * idx], b = s4[2 * idx + 1];
    union { u16 h[8]; u32x4 v; } pk;
    pk.h[0] = f2bf(a.x); pk.h[1] = f2bf(a.y); pk.h[2] = f2bf(a.z); pk.h[3] = f2bf(a.w);
    pk.h[4] = f2bf(b.x); pk.h[5] = f2bf(b.y); pk.h[6] = f2bf(b.z); pk.h[7] = f2bf(b.w);
    *(u32x4*)&xb[(size_t)idx * 8] = pk.v;
  } else if (bx < 2816) {  // W_kqv^T (1024x3072 -> 3072x1024)
    int idx = bx - 2048;
    convT_body(Wkqv, wkqvT, 1024, 3072, (idx & 15) * 64, (idx >> 4) * 64, ls);
  } else {                 // W_proj^T (1024x1024 -> 1024x1024)
    int idx = bx - 2816;
    convT_body(Wproj, wprojT, 1024, 1024, (idx & 15) * 64, (idx >> 4) * 64, ls);
  }
}

// ---- QKV GEMM: 128x128 tile, 4 waves x (64x64), BK=32, K=1024 (R8-verified) ----
__global__ __launch_bounds__(256) void qkv_gemm_kernel(
    const u16* __restrict__ A, const u16* __restrict__ Bt,
    u16* __restrict__ Qh, u16* __restrict__ Kh, u16* __restrict__ Vh, float qscale) {
  constexpr int K = 1024;
  __shared__ __align__(16) u16 As[128 * 32];
  __shared__ __align__(16) u16 Bs[128 * 32];
  int t = threadIdx.x;
  int wave = t >> 6, lane = t & 63, quad = lane >> 4, l16 = lane & 15;
  int wm = (wave >> 1) << 6, wn = (wave & 1) << 6;
  int m0 = blockIdx.x * 128, n0 = blockIdx.y * 128;
  f32x4 acc[4][4] = {};
  int u0 = t, u1 = t + 256;
  int ra0 = u0 >> 2, ca0 = ((u0 & 3) ^ ((u0 >> 3) & 3)) << 3;
  int ra1 = u1 >> 2, ca1 = ((u1 & 3) ^ ((u1 >> 3) & 3)) << 3;
  int swq = (quad ^ ((l16 >> 1) & 3)) << 3;
  for (int k0 = 0; k0 < K; k0 += 32) {
    gld_lds16(&A[(size_t)(m0 + ra0) * K + k0 + ca0], &As[u0 * 8]);
    gld_lds16(&A[(size_t)(m0 + ra1) * K + k0 + ca1], &As[u1 * 8]);
    gld_lds16(&Bt[(size_t)(n0 + ra0) * K + k0 + ca0], &Bs[u0 * 8]);
    gld_lds16(&Bt[(size_t)(n0 + ra1) * K + k0 + ca1], &Bs[u1 * 8]);
    __syncthreads();
    bf16x8 af[4], bfr[4];
    for (int r = 0; r < 4; ++r) af[r] = ld_bf8(&As[(wm + r * 16 + l16) * 32 + swq]);
    for (int c = 0; c < 4; ++c) bfr[c] = ld_bf8(&Bs[(wn + c * 16 + l16) * 32 + swq]);
    for (int r = 0; r < 4; ++r)
      for (int c = 0; c < 4; ++c)
        acc[r][c] = __builtin_amdgcn_mfma_f32_16x16x32_bf16(af[r], bfr[c], acc[r][c], 0, 0, 0);
    __syncthreads();
  }
  for (int r = 0; r < 4; ++r) {
    int rowbase = m0 + wm + r * 16 + quad * 4;
    for (int c = 0; c < 4; ++c) {
      int col = n0 + wn + c * 16 + l16;
      int seg = col >> 10;
      int cc = col & 1023;
      int h = cc >> 6, d = cc & 63;
      for (int i = 0; i < 4; ++i) {
        int row = rowbase + i;
        int b = row >> 11, tt = row & 2047;
        size_t off = (((size_t)(b * 16 + h)) * 2048 + tt) * 64 + d;
        float v = acc[r][c][i];
        if (seg == 0)      Qh[off] = f2bf(v * qscale);
        else if (seg == 1) Kh[off] = f2bf(v);
        else               Vh[off] = f2bf(v);
      }
    }
  }
}

// ---- bf16 transpose: Vh[bh][2048][64] -> Vt[bh][64][2048] ----
__global__ __launch_bounds__(256) void vT_kernel(const u16* __restrict__ Vh,
                                                 u16* __restrict__ Vt) {
  __shared__ __align__(16) u16 ls[64 * 72];
  int t = threadIdx.x;
  int t0 = blockIdx.x * 64, bh = blockIdx.y;
  const u16* in = Vh + ((size_t)bh * 2048 + t0) * 64;
  for (int u = t; u < 512; u += 256) {
    int row = u >> 3, col = (u & 7) << 3;
    *(u32x4*)&ls[row * 72 + col] = *(const u32x4*)&in[(size_t)row * 64 + col];
  }
  __syncthreads();
  for (int u = t; u < 512; u += 256) {
    int d = u >> 3, tc = (u & 7) << 3;
    union { u16 h[8]; u32x4 v; } pk;
    for (int j = 0; j < 8; ++j) pk.h[j] = ls[(tc + j) * 72 + d];
    *(u32x4*)&Vt[((size_t)bh * 64 + d) * 2048 + t0 + tc] = pk.v;
  }
}

// ---- proj GEMM: 64x64 tile, 4 waves (2x2 grid, wave tile 32x32), grid (64,16) ----
__global__ __launch_bounds__(256) void proj_gemm_kernel(
    const u16* __restrict__ A, const u16* __restrict__ Bt,
    float* __restrict__ out, const float* __restrict__ bias) {
  constexpr int K = 1024;
  __shared__ __align__(16) u16 As[64 * 32];
  __shared__ __align__(16) u16 Bs[64 * 32];
  int t = threadIdx.x;
  int wave = t >> 6, lane = t & 63, quad = lane >> 4, l16 = lane & 15;
  int wm = (wave >> 1) << 5, wn = (wave & 1) << 5;
  int m0 = blockIdx.x * 64, n0 = blockIdx.y * 64;
  f32x4 acc[2][2] = {};
  int u0 = t;  // 256 units of 16B per matrix
  int ra0 = u0 >> 2, ca0 = ((u0 & 3) ^ ((u0 >> 3) & 3)) << 3;
  int swq = (quad ^ ((l16 >> 1) & 3)) << 3;
  for (int k0 = 0; k0 < K; k0 += 32) {
    gld_lds16(&A[(size_t)(m0 + ra0) * K + k0 + ca0], &As[u0 * 8]);
    gld_lds16(&Bt[(size_t)(n0 + ra0) * K + k0 + ca0], &Bs[u0 * 8]);
    __syncthreads();
    bf16x8 af[2], bfr[2];
    for (int r = 0; r < 2; ++r) af[r] = ld_bf8(&As[(wm + r * 16 + l16) * 32 + swq]);
    for (int c = 0; c < 2; ++c) bfr[c] = ld_bf8(&Bs[(wn + c * 16 + l16) * 32 + swq]);
    for (int r = 0; r < 2; ++r)
      for (int c = 0; c < 2; ++c)
        acc[r][c] = __builtin_amdgcn_mfma_f32_16x16x32_bf16(af[r], bfr[c], acc[r][c], 0, 0, 0);
    __syncthreads();
  }
  for (int r = 0; r < 2; ++r) {
    int rowbase = m0 + wm + r * 16 + quad * 4;
    for (int c = 0; c < 2; ++c) {
      int col = n0 + wn + c * 16 + l16;
      float bv = bias[col];
      for (int i = 0; i < 4; ++i)
        out[(size_t)(rowbase + i) * 1024 + col] = acc[r][c][i] + bv;
    }
  }
}

// ---- flash attention: BQ=64, 4 waves x 16 q-rows, S^T form ----
// R11: double-buffered K/V tiles; ONE raw s_barrier per KV tile + explicit
// s_waitcnt vmcnt(0) that drains only the current tile's 4 loads (issued one full
// compute-phase earlier -> L2 latency hidden). Ps stays single-buffered: it is
// strictly wave-private (written and read at prow = wave*16+l16), no barrier needed.
// LDS 40KB -> 4 blocks/CU.
__global__ __launch_bounds__(256, 4) void flash_kernel(
    const u16* __restrict__ Qh, const u16* __restrict__ Kh, const u16* __restrict__ Vt,
    u16* __restrict__ yb, float* __restrict__ Opart) {
  __shared__ __align__(16) u16 Ks[2][64 * 64];
  __shared__ __align__(16) u16 Vs[2][64 * 64];
  __shared__ __align__(16) u16 Ps[64 * 64];
  int t = threadIdx.x, wave = t >> 6, lane = t & 63, quad = lane >> 4, l16 = lane & 15;
  int id = blockIdx.x;                 // 0..1439
  int g = id / 360, r = id % 360;
  int bh = g * 8 + (r & 7);            // same-bh jobs share an XCD
  int jx = r >> 3;                     // 0..44, longest first
  int qtile, kvs, kve, sidx = 0, half = 0;
  bool partial;
  if (jx < 19) {                       // full jobs: qtile 18..0
    qtile = 18 - jx; kvs = 0; kve = qtile + 1; partial = false;
  } else {                             // split jobs: qtile 31..19, 2 halves (<=16 iters)
    sidx = (jx - 19) >> 1; half = (jx - 19) & 1;
    qtile = 31 - sidx;
    int nkv = qtile + 1, mid = nkv >> 1;
    kvs = half ? mid : 0; kve = half ? nkv : mid; partial = true;
  }
  int q0 = qtile << 6;
  const u16* Qb = Qh + (size_t)bh * 2048 * 64;
  const u16* Kb = Kh + (size_t)bh * 2048 * 64;
  const u16* Vb = Vt + (size_t)bh * 64 * 2048;
  bf16x8 qa0, qa1;  // B-operand frags (S^T form)
  {
    int qrow = q0 + wave * 16 + l16;
    qa0 = ld_bf8(&Qb[(size_t)qrow * 64 + quad * 8]);
    qa1 = ld_bf8(&Qb[(size_t)qrow * 64 + 32 + quad * 8]);
  }
  f32x4 oacc[4] = {};
  float lsum = 0.f;
  int u0 = wave * 128 + lane, u1 = u0 + 64;
  int r0 = u0 >> 3, p0 = u0 & 7, cb0 = (p0 - r0) & 7;
  int r1s = u1 >> 3, p1 = u1 & 7, cb1 = (p1 - r1s) & 7;
  // prologue: stage first tile into buffer 0 (latency not hidden, once per job)
  {
    int kv0 = kvs << 6;
    gld_lds16(&Kb[(size_t)(kv0 + r0) * 64 + cb0 * 8], &Ks[0][u0 * 8]);
    gld_lds16(&Kb[(size_t)(kv0 + r1s) * 64 + cb1 * 8], &Ks[0][u1 * 8]);
    gld_lds16(&Vb[(size_t)r0 * 2048 + kv0 + cb0 * 8], &Vs[0][u0 * 8]);
    gld_lds16(&Vb[(size_t)r1s * 2048 + kv0 + cb1 * 8], &Vs[0][u1 * 8]);
  }
  for (int j = kvs; j < kve; ++j) {
    int p = (j - kvs) & 1;
    // tile-j loads were issued one compute-phase ago; only they are outstanding.
    asm volatile("s_waitcnt vmcnt(0)" ::: "memory");
    __builtin_amdgcn_s_barrier();      // raw: no compiler-forced drain of next prefetch
    asm volatile("" ::: "memory");
    if (j + 1 < kve) {                 // prefetch tile j+1 into the other buffer:
      int kn0 = (j + 1) << 6;          // safe — barrier proved all waves finished
      int pn = p ^ 1;                  // reading buf[p^1] (tile j-1) last iteration.
      gld_lds16(&Kb[(size_t)(kn0 + r0) * 64 + cb0 * 8], &Ks[pn][u0 * 8]);
      gld_lds16(&Kb[(size_t)(kn0 + r1s) * 64 + cb1 * 8], &Ks[pn][u1 * 8]);
      gld_lds16(&Vb[(size_t)r0 * 2048 + kn0 + cb0 * 8], &Vs[pn][u0 * 8]);
      gld_lds16(&Vb[(size_t)r1s * 2048 + kn0 + cb1 * 8], &Vs[pn][u1 * 8]);
    }
    int kv0 = j << 6;
    bool maskit = (j == qtile);
    const u16* Ksp = Ks[p];
    const u16* Vsp = Vs[p];
    for (int c = 0; c < 4; ++c) {
      int krow = c * 16 + l16;
      bf16x8 kb0 = ld_bf8(&Ksp[krow * 64 + ((quad + krow) & 7) * 8]);
      bf16x8 kb1 = ld_bf8(&Ksp[krow * 64 + ((quad + 4 + krow) & 7) * 8]);
      f32x4 z = {0.f, 0.f, 0.f, 0.f};
      __builtin_amdgcn_s_setprio(1);
      z = __builtin_amdgcn_mfma_f32_16x16x32_bf16(kb0, qa0, z, 0, 0, 0);
      z = __builtin_amdgcn_mfma_f32_16x16x32_bf16(kb1, qa1, z, 0, 0, 0);
      __builtin_amdgcn_s_setprio(0);
      int prow = wave * 16 + l16;
      union { u16 hh[4]; u16x4 v; } pk;
      if (maskit) {
        int qg = q0 + prow;
        for (int i = 0; i < 4; ++i) {
          float pexp = __builtin_amdgcn_exp2f(z[i]);
          if (kv0 + c * 16 + quad * 4 + i > qg) pexp = 0.f;
          lsum += pexp;
          pk.hh[i] = f2bf(pexp);
        }
      } else {
        for (int i = 0; i < 4; ++i) {
          float pexp = __builtin_amdgcn_exp2f(z[i]);
          lsum += pexp;
          pk.hh[i] = f2bf(pexp);
        }
      }
      *(u16x4*)&Ps[prow * 64 + ((2 * c + (quad >> 1) + prow) & 7) * 8 + (quad & 1) * 4] = pk.v;
    }
    int prow = wave * 16 + l16;
    bf16x8 pa0 = ld_bf8(&Ps[prow * 64 + ((quad + prow) & 7) * 8]);      // A-frag readback
    bf16x8 pa1 = ld_bf8(&Ps[prow * 64 + ((quad + 4 + prow) & 7) * 8]);
    for (int dt = 0; dt < 4; ++dt) {
      int vrow = dt * 16 + l16;
      bf16x8 vb0 = ld_bf8(&Vsp[vrow * 64 + ((quad + vrow) & 7) * 8]);
      bf16x8 vb1 = ld_bf8(&Vsp[vrow * 64 + ((quad + 4 + vrow) & 7) * 8]);
      __builtin_amdgcn_s_setprio(1);
      oacc[dt] = __builtin_amdgcn_mfma_f32_16x16x32_bf16(pa0, vb0, oacc[dt], 0, 0, 0);
      oacc[dt] = __builtin_amdgcn_mfma_f32_16x16x32_bf16(pa1, vb1, oacc[dt], 0, 0, 0);
      __builtin_amdgcn_s_setprio(0);
    }
  }
  lsum += __shfl_xor(lsum, 16);
  lsum += __shfl_xor(lsum, 32);
  if (partial) {
    float* Op = Opart + ((size_t)(bh * 13 + sidx) * 2 + half) * 4160;
    for (int dt = 0; dt < 4; ++dt)
      for (int i = 0; i < 4; ++i)
        Op[(wave * 16 + quad * 4 + i) * 64 + dt * 16 + l16] = oacc[dt][i];
    if (quad == 0) Op[4096 + wave * 16 + l16] = lsum;
  } else {
    int b = bh >> 4, h = bh & 15;
    for (int i = 0; i < 4; ++i) {
      float inv = 1.0f / __shfl(lsum, quad * 4 + i);
      int qq = q0 + wave * 16 + quad * 4 + i;
      size_t rowoff = ((size_t)(b * 2048 + qq)) * 1024 + h * 64;
      for (int dt = 0; dt < 4; ++dt)
        yb[rowoff + dt * 16 + l16] = f2bf(oacc[dt][i] * inv);
    }
  }
}

// ---- combine split halves: O = O0+O1, l = l0+l1, write normalized bf16 ----
__global__ __launch_bounds__(256) void combine_kernel(const float* __restrict__ Opart,
                                                      u16* __restrict__ yb) {
  int sidx = blockIdx.x, bh = blockIdx.y, t = threadIdx.x;
  int qtile = 31 - sidx;
  const float* A = Opart + (size_t)(bh * 13 + sidx) * 2 * 4160;
  const float* Bp = A + 4160;
  int q = t >> 2, d0 = (t & 3) << 4;
  float inv = 1.0f / (A[4096 + q] + Bp[4096 + q]);
  int b = bh >> 4, h = bh & 15;
  size_t off = ((size_t)(b * 2048 + (qtile << 6) + q)) * 1024 + h * 64 + d0;
  union { u16 hh[16]; u32x4 v[2]; } pk;
  for (int k = 0; k < 16; ++k)
    pk.hh[k] = f2bf((A[q * 64 + d0 + k] + Bp[q * 64 + d0 + k]) * inv);
  *(u32x4*)&yb[off] = pk.v[0];
  *(u32x4*)&yb[off + 8] = pk.v[1];
}

extern "C" void kernel_launch(void* const* d_in, const int* in_sizes, int n_in,
                              void* d_out, int out_size, void* d_ws, size_t ws_size,
                              hipStream_t stream) {
  const float* x     = (const float*)d_in[0];
  const float* Wkqv  = (const float*)d_in[1];
  const float* Wproj = (const float*)d_in[2];
  const float* bproj = (const float*)d_in[3];
  float* out = (float*)d_out;

  u16* ws     = (u16*)d_ws;                       // 48 MiB total scratch
  u16* xb     = ws;                               // 4096x1024 bf16 = 8.39 MB (dead after qkv)
  u16* wkqvT  = xb + (size_t)4096 * 1024;         // 3072x1024 = 6.29 MB (dead after qkv)
  u16* wprojT = wkqvT + (size_t)3072 * 1024;      // 1024x1024 (W_proj^T) -- LIVE to the end
  u16* Qh     = wprojT + (size_t)1024 * 1024;     // [32][2048][64], pre-scaled
  u16* Kh     = Qh + (size_t)32 * 2048 * 64;      // [32][2048][64]
  u16* Vt     = Kh + (size_t)32 * 2048 * 64;      // [32][64][2048]
  u16* yb     = Vt + (size_t)32 * 2048 * 64;      // 4096x1024 attn out; doubles as Vh
  u16* Vh     = yb;
  // Opart: 32 bh x 13 split-tiles x 2 halves x 4160 fp32 = 13.84 MB — inside dead
  // xb+wkqvT (14.68 MB); wprojT untouched.
  float* Opart = (float*)ws;

  const float QSCALE = 0.18033688011112042f;  // (1/sqrt(64)) * log2(e)

  prep_kernel<<<3072, 256, 0, stream>>>(x, Wkqv, Wproj, xb, wkqvT, wprojT);
  qkv_gemm_kernel<<<dim3(32, 24), 256, 0, stream>>>(xb, wkqvT, Qh, Kh, Vh, QSCALE);
  vT_kernel<<<dim3(32, 32), 256, 0, stream>>>(Vh, Vt);
  flash_kernel<<<1440, 256, 0, stream>>>(Qh, Kh, Vt, yb, Opart);
  combine_kernel<<<dim3(13, 32), 256, 0, stream>>>(Opart, yb);
  proj_gemm_kernel<<<dim3(64, 16), 256, 0, stream>>>(yb, wprojT, out, bproj);
}

// Round 2
// 180.984 us; speedup vs baseline: 1.0015x; 1.0015x over previous
//
#include <hip/hip_runtime.h>

// Causal MHA forward, B=2 T=2048 C=1024 H=16 hs=64, fp32 in/out, bf16 MFMA internally.
// R12: flash kernel reworked — PV computed as O^T = V^T * P^T with P^T fed DIRECTLY from
// registers (v_cvt_pk_bf16_f32 pairs; k-axis permutation matched on the V^T reads), which
// eliminates the Ps LDS round-trip (8KB buffer, 4 writes + 2 reads per wave-iter) and the
// manual f2bf packing (~64 VALU/thread-iter). Loop sync reverted to R10's proven
// single-buffer 2-syncthreads form (R11 dbuf traded TLP for ILP at a net loss:
// 42.4 -> 45.0us). Other kernels unchanged.

typedef unsigned short u16;
typedef unsigned int u32;
typedef __bf16 bf16x8 __attribute__((ext_vector_type(8)));
typedef float f32x4 __attribute__((ext_vector_type(4)));
typedef u32 u32x4 __attribute__((ext_vector_type(4)));
typedef u32 u32x2 __attribute__((ext_vector_type(2)));
typedef u16 u16x4 __attribute__((ext_vector_type(4)));

__device__ __forceinline__ u16 f2bf(float f) {
  u32 u = __float_as_uint(f);
  u32 r = u + 0x7FFFu + ((u >> 16) & 1u);  // RNE, finite inputs only
  return (u16)(r >> 16);
}

// packed f32x2 -> bf16x2 (low = a, high = b)
__device__ __forceinline__ u32 cvt_pk_bf16(float a, float b) {
  u32 r;
  asm("v_cvt_pk_bf16_f32 %0, %1, %2" : "=v"(r) : "v"(a), "v"(b));
  return r;
}

__device__ __forceinline__ bf16x8 ld_bf8(const u16* p) {
  union { u32x4 u; bf16x8 b; } x;
  x.u = *(const u32x4*)p;
  return x.b;
}

__device__ __forceinline__ void gld_lds16(const u16* g, u16* l) {
  __builtin_amdgcn_global_load_lds(
      (const __attribute__((address_space(1))) u32*)g,
      (__attribute__((address_space(3))) u32*)l, 16, 0, 0);
}

// ---- merged prep: fp32->bf16 x-convert + both weight transpose-converts ----
__device__ __forceinline__ void convT_body(const float* __restrict__ src,
                                           u16* __restrict__ dst, int R, int Cc,
                                           int r0, int c0, float* ls /*64x65*/) {
  int t = threadIdx.x;
  for (int u = t; u < 1024; u += 256) {
    int r = u >> 4, cs = (u & 15) << 2;
    float4 v = *(const float4*)&src[(size_t)(r0 + r) * Cc + (c0 + cs)];
    ls[r * 65 + cs] = v.x; ls[r * 65 + cs + 1] = v.y;
    ls[r * 65 + cs + 2] = v.z; ls[r * 65 + cs + 3] = v.w;
  }
  __syncthreads();
  for (int u = t; u < 1024; u += 256) {
    int n = u >> 4, ks = (u & 15) << 2;
    u16x4 o;
    o.x = f2bf(ls[ks * 65 + n]); o.y = f2bf(ls[(ks + 1) * 65 + n]);
    o.z = f2bf(ls[(ks + 2) * 65 + n]); o.w = f2bf(ls[(ks + 3) * 65 + n]);
    *(u16x4*)&dst[(size_t)(c0 + n) * R + (r0 + ks)] = o;
  }
}

__global__ __launch_bounds__(256) void prep_kernel(
    const float* __restrict__ x, const float* __restrict__ Wkqv,
    const float* __restrict__ Wproj, u16* __restrict__ xb,
    u16* __restrict__ wkqvT, u16* __restrict__ wprojT) {
  __shared__ float ls[64 * 65];
  int bx = blockIdx.x;
  if (bx < 2048) {  // x -> bf16, 8 elems/thread
    int idx = bx * 256 + threadIdx.x;
    const float4* s4 = (const float4*)x;
    float4 a = s4[2 * idx], b = s4[2 * idx + 1];
    union { u16 h[8]; u32x4 v; } pk;
    pk.h[0] = f2bf(a.x); pk.h[1] = f2bf(a.y); pk.h[2] = f2bf(a.z); pk.h[3] = f2bf(a.w);
    pk.h[4] = f2bf(b.x); pk.h[5] = f2bf(b.y); pk.h[6] = f2bf(b.z); pk.h[7] = f2bf(b.w);
    *(u32x4*)&xb[(size_t)idx * 8] = pk.v;
  } else if (bx < 2816) {  // W_kqv^T (1024x3072 -> 3072x1024)
    int idx = bx - 2048;
    convT_body(Wkqv, wkqvT, 1024, 3072, (idx & 15) * 64, (idx >> 4) * 64, ls);
  } else {                 // W_proj^T (1024x1024 -> 1024x1024)
    int idx = bx - 2816;
    convT_body(Wproj, wprojT, 1024, 1024, (idx & 15) * 64, (idx >> 4) * 64, ls);
  }
}

// ---- QKV GEMM: 128x128 tile, 4 waves x (64x64), BK=32, K=1024 (R8-verified) ----
__global__ __launch_bounds__(256) void qkv_gemm_kernel(
    const u16* __restrict__ A, const u16* __restrict__ Bt,
    u16* __restrict__ Qh, u16* __restrict__ Kh, u16* __restrict__ Vh, float qscale) {
  constexpr int K = 1024;
  __shared__ __align__(16) u16 As[128 * 32];
  __shared__ __align__(16) u16 Bs[128 * 32];
  int t = threadIdx.x;
  int wave = t >> 6, lane = t & 63, quad = lane >> 4, l16 = lane & 15;
  int wm = (wave >> 1) << 6, wn = (wave & 1) << 6;
  int m0 = blockIdx.x * 128, n0 = blockIdx.y * 128;
  f32x4 acc[4][4] = {};
  int u0 = t, u1 = t + 256;
  int ra0 = u0 >> 2, ca0 = ((u0 & 3) ^ ((u0 >> 3) & 3)) << 3;
  int ra1 = u1 >> 2, ca1 = ((u1 & 3) ^ ((u1 >> 3) & 3)) << 3;
  int swq = (quad ^ ((l16 >> 1) & 3)) << 3;
  for (int k0 = 0; k0 < K; k0 += 32) {
    gld_lds16(&A[(size_t)(m0 + ra0) * K + k0 + ca0], &As[u0 * 8]);
    gld_lds16(&A[(size_t)(m0 + ra1) * K + k0 + ca1], &As[u1 * 8]);
    gld_lds16(&Bt[(size_t)(n0 + ra0) * K + k0 + ca0], &Bs[u0 * 8]);
    gld_lds16(&Bt[(size_t)(n0 + ra1) * K + k0 + ca1], &Bs[u1 * 8]);
    __syncthreads();
    bf16x8 af[4], bfr[4];
    for (int r = 0; r < 4; ++r) af[r] = ld_bf8(&As[(wm + r * 16 + l16) * 32 + swq]);
    for (int c = 0; c < 4; ++c) bfr[c] = ld_bf8(&Bs[(wn + c * 16 + l16) * 32 + swq]);
    for (int r = 0; r < 4; ++r)
      for (int c = 0; c < 4; ++c)
        acc[r][c] = __builtin_amdgcn_mfma_f32_16x16x32_bf16(af[r], bfr[c], acc[r][c], 0, 0, 0);
    __syncthreads();
  }
  for (int r = 0; r < 4; ++r) {
    int rowbase = m0 + wm + r * 16 + quad * 4;
    for (int c = 0; c < 4; ++c) {
      int col = n0 + wn + c * 16 + l16;
      int seg = col >> 10;
      int cc = col & 1023;
      int h = cc >> 6, d = cc & 63;
      for (int i = 0; i < 4; ++i) {
        int row = rowbase + i;
        int b = row >> 11, tt = row & 2047;
        size_t off = (((size_t)(b * 16 + h)) * 2048 + tt) * 64 + d;
        float v = acc[r][c][i];
        if (seg == 0)      Qh[off] = f2bf(v * qscale);
        else if (seg == 1) Kh[off] = f2bf(v);
        else               Vh[off] = f2bf(v);
      }
    }
  }
}

// ---- bf16 transpose: Vh[bh][2048][64] -> Vt[bh][64][2048] ----
__global__ __launch_bounds__(256) void vT_kernel(const u16* __restrict__ Vh,
                                                 u16* __restrict__ Vt) {
  __shared__ __align__(16) u16 ls[64 * 72];
  int t = threadIdx.x;
  int t0 = blockIdx.x * 64, bh = blockIdx.y;
  const u16* in = Vh + ((size_t)bh * 2048 + t0) * 64;
  for (int u = t; u < 512; u += 256) {
    int row = u >> 3, col = (u & 7) << 3;
    *(u32x4*)&ls[row * 72 + col] = *(const u32x4*)&in[(size_t)row * 64 + col];
  }
  __syncthreads();
  for (int u = t; u < 512; u += 256) {
    int d = u >> 3, tc = (u & 7) << 3;
    union { u16 h[8]; u32x4 v; } pk;
    for (int j = 0; j < 8; ++j) pk.h[j] = ls[(tc + j) * 72 + d];
    *(u32x4*)&Vt[((size_t)bh * 64 + d) * 2048 + t0 + tc] = pk.v;
  }
}

// ---- proj GEMM: 64x64 tile, 4 waves (2x2 grid, wave tile 32x32), grid (64,16) ----
__global__ __launch_bounds__(256) void proj_gemm_kernel(
    const u16* __restrict__ A, const u16* __restrict__ Bt,
    float* __restrict__ out, const float* __restrict__ bias) {
  constexpr int K = 1024;
  __shared__ __align__(16) u16 As[64 * 32];
  __shared__ __align__(16) u16 Bs[64 * 32];
  int t = threadIdx.x;
  int wave = t >> 6, lane = t & 63, quad = lane >> 4, l16 = lane & 15;
  int wm = (wave >> 1) << 5, wn = (wave & 1) << 5;
  int m0 = blockIdx.x * 64, n0 = blockIdx.y * 64;
  f32x4 acc[2][2] = {};
  int u0 = t;  // 256 units of 16B per matrix
  int ra0 = u0 >> 2, ca0 = ((u0 & 3) ^ ((u0 >> 3) & 3)) << 3;
  int swq = (quad ^ ((l16 >> 1) & 3)) << 3;
  for (int k0 = 0; k0 < K; k0 += 32) {
    gld_lds16(&A[(size_t)(m0 + ra0) * K + k0 + ca0], &As[u0 * 8]);
    gld_lds16(&Bt[(size_t)(n0 + ra0) * K + k0 + ca0], &Bs[u0 * 8]);
    __syncthreads();
    bf16x8 af[2], bfr[2];
    for (int r = 0; r < 2; ++r) af[r] = ld_bf8(&As[(wm + r * 16 + l16) * 32 + swq]);
    for (int c = 0; c < 2; ++c) bfr[c] = ld_bf8(&Bs[(wn + c * 16 + l16) * 32 + swq]);
    for (int r = 0; r < 2; ++r)
      for (int c = 0; c < 2; ++c)
        acc[r][c] = __builtin_amdgcn_mfma_f32_16x16x32_bf16(af[r], bfr[c], acc[r][c], 0, 0, 0);
    __syncthreads();
  }
  for (int r = 0; r < 2; ++r) {
    int rowbase = m0 + wm + r * 16 + quad * 4;
    for (int c = 0; c < 2; ++c) {
      int col = n0 + wn + c * 16 + l16;
      float bv = bias[col];
      for (int i = 0; i < 4; ++i)
        out[(size_t)(rowbase + i) * 1024 + col] = acc[r][c][i] + bv;
    }
  }
}

// ---- flash attention: BQ=64, 4 waves x 16 q-rows, S^T form, register-P PV ----
// QK^T gives z = S^T frag (row kv=c*16+quad*4+i, col q=l16). cvt_pk packs z into
// w[c][t] (bf16x2 at kv=c*16+quad*4+{2t,2t+1}). PV computed as O^T = V^T * P^T with
// k-slot permutation pi(quad,j) = c*16 + quad*4 + (j&3), c = 2h + (j>>2):
//   B-frag (P^T) = [w[2h][0], w[2h][1], w[2h+1][0], w[2h+1][1]]  (own lane, no xlane ops)
//   A-frag (V^T) = two 8B LDS reads at the same permuted kv positions.
// O^T layout: oacc[dt][i] = O[q=l16][d=dt*16+quad*4+i]; lsum (col sum, q=l16) needs no
// shfl for the normalize. Ps buffer gone: LDS 16KB.
__global__ __launch_bounds__(256, 6) void flash_kernel(
    const u16* __restrict__ Qh, const u16* __restrict__ Kh, const u16* __restrict__ Vt,
    u16* __restrict__ yb, float* __restrict__ Opart) {
  __shared__ __align__(16) u16 Ks[64 * 64];
  __shared__ __align__(16) u16 Vs[64 * 64];
  int t = threadIdx.x, wave = t >> 6, lane = t & 63, quad = lane >> 4, l16 = lane & 15;
  int id = blockIdx.x;                 // 0..1439
  int g = id / 360, r = id % 360;
  int bh = g * 8 + (r & 7);            // same-bh jobs share an XCD
  int jx = r >> 3;                     // 0..44, longest first
  int qtile, kvs, kve, sidx = 0, half = 0;
  bool partial;
  if (jx < 19) {                       // full jobs: qtile 18..0
    qtile = 18 - jx; kvs = 0; kve = qtile + 1; partial = false;
  } else {                             // split jobs: qtile 31..19, 2 halves (<=16 iters)
    sidx = (jx - 19) >> 1; half = (jx - 19) & 1;
    qtile = 31 - sidx;
    int nkv = qtile + 1, mid = nkv >> 1;
    kvs = half ? mid : 0; kve = half ? nkv : mid; partial = true;
  }
  int q0 = qtile << 6;
  const u16* Qb = Qh + (size_t)bh * 2048 * 64;
  const u16* Kb = Kh + (size_t)bh * 2048 * 64;
  const u16* Vb = Vt + (size_t)bh * 64 * 2048;
  bf16x8 qa0, qa1;  // B-operand frags for QK (S^T form)
  {
    int qrow = q0 + wave * 16 + l16;
    qa0 = ld_bf8(&Qb[(size_t)qrow * 64 + quad * 8]);
    qa1 = ld_bf8(&Qb[(size_t)qrow * 64 + 32 + quad * 8]);
  }
  f32x4 oacc[4] = {};
  float lsum = 0.f;
  int u0 = wave * 128 + lane, u1 = u0 + 64;
  int r0 = u0 >> 3, p0 = u0 & 7, cb0 = (p0 - r0) & 7;
  int r1s = u1 >> 3, p1 = u1 & 7, cb1 = (p1 - r1s) & 7;
  // V^T read offsets for the permuted A-frags (8B each), per h (kv half):
  //   lo chunk = h*4 + (quad>>1), hi chunk = lo + 2; sub-offset (quad&1)*4 u16.
  int vsub = (quad & 1) * 4;
  int vc0 = quad >> 1;
  for (int j = kvs; j < kve; ++j) {
    int kv0 = j << 6;
    __syncthreads();  // previous tile fully consumed
    gld_lds16(&Kb[(size_t)(kv0 + r0) * 64 + cb0 * 8], &Ks[u0 * 8]);
    gld_lds16(&Kb[(size_t)(kv0 + r1s) * 64 + cb1 * 8], &Ks[u1 * 8]);
    gld_lds16(&Vb[(size_t)r0 * 2048 + kv0 + cb0 * 8], &Vs[u0 * 8]);
    gld_lds16(&Vb[(size_t)r1s * 2048 + kv0 + cb1 * 8], &Vs[u1 * 8]);
    __syncthreads();  // vmcnt drain -> tiles ready
    bool maskit = (j == qtile);
    u32 w[4][2];
    for (int c = 0; c < 4; ++c) {
      int krow = c * 16 + l16;
      bf16x8 kb0 = ld_bf8(&Ks[krow * 64 + ((quad + krow) & 7) * 8]);
      bf16x8 kb1 = ld_bf8(&Ks[krow * 64 + ((quad + 4 + krow) & 7) * 8]);
      f32x4 z = {0.f, 0.f, 0.f, 0.f};
      z = __builtin_amdgcn_mfma_f32_16x16x32_bf16(kb0, qa0, z, 0, 0, 0);
      z = __builtin_amdgcn_mfma_f32_16x16x32_bf16(kb1, qa1, z, 0, 0, 0);
      float pexp[4];
      if (maskit) {
        int qg = q0 + wave * 16 + l16;   // this lane's q column
        for (int i = 0; i < 4; ++i) {
          float p = __builtin_amdgcn_exp2f(z[i]);
          if (kv0 + c * 16 + quad * 4 + i > qg) p = 0.f;
          lsum += p;
          pexp[i] = p;
        }
      } else {
        for (int i = 0; i < 4; ++i) {
          float p = __builtin_amdgcn_exp2f(z[i]);
          lsum += p;
          pexp[i] = p;
        }
      }
      w[c][0] = cvt_pk_bf16(pexp[0], pexp[1]);
      w[c][1] = cvt_pk_bf16(pexp[2], pexp[3]);
    }
    // P^T B-frags straight from registers (k-permutation pi)
    union { u32 uu[4]; bf16x8 b; } pf0, pf1;
    pf0.uu[0] = w[0][0]; pf0.uu[1] = w[0][1]; pf0.uu[2] = w[1][0]; pf0.uu[3] = w[1][1];
    pf1.uu[0] = w[2][0]; pf1.uu[1] = w[2][1]; pf1.uu[2] = w[3][0]; pf1.uu[3] = w[3][1];
    for (int dt = 0; dt < 4; ++dt) {
      int vrow = dt * 16 + l16;          // d = dt*16 + l16 (A row)
      int rbase = vrow * 64 + vsub;
      // h = 0: kv chunks (vc0, vc0+2); h = 1: (vc0+4, vc0+6)  (pre-rotation)
      union { u32x2 lo2; struct { u32 a, b; }; } h0lo, h0hi, h1lo, h1hi;
      h0lo.lo2 = *(const u32x2*)&Vs[rbase + (((vc0)     + vrow) & 7) * 8];
      h0hi.lo2 = *(const u32x2*)&Vs[rbase + (((vc0 + 2) + vrow) & 7) * 8];
      h1lo.lo2 = *(const u32x2*)&Vs[rbase + (((vc0 + 4) + vrow) & 7) * 8];
      h1hi.lo2 = *(const u32x2*)&Vs[rbase + (((vc0 + 6) + vrow) & 7) * 8];
      union { u32 uu[4]; bf16x8 b; } va0, va1;
      va0.uu[0] = h0lo.a; va0.uu[1] = h0lo.b; va0.uu[2] = h0hi.a; va0.uu[3] = h0hi.b;
      va1.uu[0] = h1lo.a; va1.uu[1] = h1lo.b; va1.uu[2] = h1hi.a; va1.uu[3] = h1hi.b;
      oacc[dt] = __builtin_amdgcn_mfma_f32_16x16x32_bf16(va0.b, pf0.b, oacc[dt], 0, 0, 0);
      oacc[dt] = __builtin_amdgcn_mfma_f32_16x16x32_bf16(va1.b, pf1.b, oacc[dt], 0, 0, 0);
    }
  }
  lsum += __shfl_xor(lsum, 16);
  lsum += __shfl_xor(lsum, 32);          // now: full column sum for q = l16, all lanes
  if (partial) {
    float* Op = Opart + ((size_t)(bh * 13 + sidx) * 2 + half) * 4160;
    int qloc = wave * 16 + l16;
    for (int dt = 0; dt < 4; ++dt)
      *(f32x4*)&Op[qloc * 64 + dt * 16 + quad * 4] = oacc[dt];
    if (quad == 0) Op[4096 + qloc] = lsum;
  } else {
    int b = bh >> 4, hd = bh & 15;
    float inv = 1.0f / lsum;
    int qq = q0 + wave * 16 + l16;
    size_t rowoff = ((size_t)(b * 2048 + qq)) * 1024 + hd * 64;
    for (int dt = 0; dt < 4; ++dt) {
      u32x2 pr;
      pr.x = cvt_pk_bf16(oacc[dt][0] * inv, oacc[dt][1] * inv);
      pr.y = cvt_pk_bf16(oacc[dt][2] * inv, oacc[dt][3] * inv);
      *(u32x2*)&yb[rowoff + dt * 16 + quad * 4] = pr;
    }
  }
}

// ---- combine split halves: O = O0+O1, l = l0+l1, write normalized bf16 ----
__global__ __launch_bounds__(256) void combine_kernel(const float* __restrict__ Opart,
                                                      u16* __restrict__ yb) {
  int sidx = blockIdx.x, bh = blockIdx.y, t = threadIdx.x;
  int qtile = 31 - sidx;
  const float* A = Opart + (size_t)(bh * 13 + sidx) * 2 * 4160;
  const float* Bp = A + 4160;
  int q = t >> 2, d0 = (t & 3) << 4;
  float inv = 1.0f / (A[4096 + q] + Bp[4096 + q]);
  int b = bh >> 4, h = bh & 15;
  size_t off = ((size_t)(b * 2048 + (qtile << 6) + q)) * 1024 + h * 64 + d0;
  union { u16 hh[16]; u32x4 v[2]; } pk;
  for (int k = 0; k < 16; ++k)
    pk.hh[k] = f2bf((A[q * 64 + d0 + k] + Bp[q * 64 + d0 + k]) * inv);
  *(u32x4*)&yb[off] = pk.v[0];
  *(u32x4*)&yb[off + 8] = pk.v[1];
}

extern "C" void kernel_launch(void* const* d_in, const int* in_sizes, int n_in,
                              void* d_out, int out_size, void* d_ws, size_t ws_size,
                              hipStream_t stream) {
  const float* x     = (const float*)d_in[0];
  const float* Wkqv  = (const float*)d_in[1];
  const float* Wproj = (const float*)d_in[2];
  const float* bproj = (const float*)d_in[3];
  float* out = (float*)d_out;

  u16* ws     = (u16*)d_ws;                       // 48 MiB total scratch
  u16* xb     = ws;                               // 4096x1024 bf16 = 8.39 MB (dead after qkv)
  u16* wkqvT  = xb + (size_t)4096 * 1024;         // 3072x1024 = 6.29 MB (dead after qkv)
  u16* wprojT = wkqvT + (size_t)3072 * 1024;      // 1024x1024 (W_proj^T) -- LIVE to the end
  u16* Qh     = wprojT + (size_t)1024 * 1024;     // [32][2048][64], pre-scaled
  u16* Kh     = Qh + (size_t)32 * 2048 * 64;      // [32][2048][64]
  u16* Vt     = Kh + (size_t)32 * 2048 * 64;      // [32][64][2048]
  u16* yb     = Vt + (size_t)32 * 2048 * 64;      // 4096x1024 attn out; doubles as Vh
  u16* Vh     = yb;
  // Opart: 32 bh x 13 split-tiles x 2 halves x 4160 fp32 = 13.84 MB — inside dead
  // xb+wkqvT (14.68 MB); wprojT untouched.
  float* Opart = (float*)ws;

  const float QSCALE = 0.18033688011112042f;  // (1/sqrt(64)) * log2(e)

  prep_kernel<<<3072, 256, 0, stream>>>(x, Wkqv, Wproj, xb, wkqvT, wprojT);
  qkv_gemm_kernel<<<dim3(32, 24), 256, 0, stream>>>(xb, wkqvT, Qh, Kh, Vh, QSCALE);
  vT_kernel<<<dim3(32, 32), 256, 0, stream>>>(Vh, Vt);
  flash_kernel<<<1440, 256, 0, stream>>>(Qh, Kh, Vt, yb, Opart);
  combine_kernel<<<dim3(13, 32), 256, 0, stream>>>(Opart, yb);
  proj_gemm_kernel<<<dim3(64, 16), 256, 0, stream>>>(yb, wprojT, out, bproj);
}